// Round 1
// baseline (1792.636 us; speedup 1.0000x reference)
//
#include <hip/hip_runtime.h>

// Problem constants
constexpr int HD = 4096;   // hidden dim
constexpr int TD = 8192;   // tokens

typedef __bf16 bf16;
typedef __bf16 bf16x4 __attribute__((ext_vector_type(4)));
typedef __bf16 bf16x8 __attribute__((ext_vector_type(8)));
typedef float  f32x4  __attribute__((ext_vector_type(4)));

// ---------------------------------------------------------------------------
// fp8 e4m3fn round-to-nearest-even of a non-negative value already clipped to
// [0, 448].  ulp = 2^(e-3) for normals (e >= -6), 2^-9 for subnormals.
__device__ __forceinline__ float e4m3_round(float v) {
    if (!(v > 0.0f)) return 0.0f;
    unsigned b = __float_as_uint(v);
    int exp = (int)((b >> 23) & 255) - 127;
    int shift = (exp < -6) ? -9 : (exp - 3);          // shift in [-9, 5]
    float sc  = __uint_as_float((unsigned)(127 + shift) << 23);  // 2^shift
    float isc = __uint_as_float((unsigned)(127 - shift) << 23);  // 2^-shift
    return rintf(v * isc) * sc;                        // RNE on the grid
}

// fp4 e2m1 round-to-nearest, ties away from zero (matches jnp searchsorted
// side='right' on midpoints [.25,.75,1.25,1.75,2.5,3.5,5.0]).
__device__ __forceinline__ float fp4_round(float x) {
    float s = (x < 0.0f) ? -1.0f : 1.0f;
    float a = fminf(fabsf(x), 6.0f);
    float v;
    if      (a < 0.25f) v = 0.0f;
    else if (a < 0.75f) v = 0.5f;
    else if (a < 1.25f) v = 1.0f;
    else if (a < 1.75f) v = 1.5f;
    else if (a < 2.5f)  v = 2.0f;
    else if (a < 3.5f)  v = 3.0f;
    else if (a < 5.0f)  v = 4.0f;
    else                v = 6.0f;
    return s * v;
}

// async global->LDS, 16 bytes per lane; LDS dest must be wave-uniform base.
__device__ __forceinline__ void load_lds16(const void* g, void* l) {
    typedef __attribute__((address_space(1))) const void gv_t;
    typedef __attribute__((address_space(3))) void lv_t;
    __builtin_amdgcn_global_load_lds((gv_t*)g, (lv_t*)l, 16, 0, 0);
}

// ---------------------------------------------------------------------------
// Weight quant+dequant: w[3][H][H] fp32 -> Bdeq[3][H][H] bf16 (= q*sc exactly).
// One thread per float4; 4 consecutive lanes form one 16-elem quant block.
__global__ __launch_bounds__(256) void quant_w_kernel(
        const float* __restrict__ w, const float* __restrict__ wg,
        bf16* __restrict__ bdeq) {
    const size_t t4 = (size_t)blockIdx.x * 256 + threadIdx.x;   // float4 index
    const int mat = (int)(t4 >> 22);                            // / (H*H/4)
    const float gs = wg[mat];
    const float4 v = ((const float4*)w)[t4];
    float am = fmaxf(fmaxf(fabsf(v.x), fabsf(v.y)), fmaxf(fabsf(v.z), fabsf(v.w)));
    am = fmaxf(am, __shfl_xor(am, 1));
    am = fmaxf(am, __shfl_xor(am, 2));
    const float sc = e4m3_round(fminf((am / 6.0f) * gs, 448.0f));
    bf16x4 o;
    if (sc > 0.0f) {
        o[0] = (bf16)(fp4_round(v.x * gs / sc) * sc);
        o[1] = (bf16)(fp4_round(v.y * gs / sc) * sc);
        o[2] = (bf16)(fp4_round(v.z * gs / sc) * sc);
        o[3] = (bf16)(fp4_round(v.w * gs / sc) * sc);
    } else {
        o[0] = o[1] = o[2] = o[3] = (bf16)0.0f;
    }
    ((bf16x4*)bdeq)[t4] = o;
}

// ---------------------------------------------------------------------------
// Fused (relu) + rmsnorm + activation quant-dequant.
// mode 0: in=hidden, relu, write resid_out(fp32), quant -> qout(bf16)
// mode 1: in=x,      quant -> qout(bf16)
// mode 2: in=x,      write y(fp32) -> yout (final output; in-place safe)
// One block per row; thread t handles float4s at c*1024 + t*4 (coalesced);
// 4 consecutive lanes cover one 16-elem quant block.
__global__ __launch_bounds__(256) void rms_quant_kernel(
        const float* __restrict__ in, float* __restrict__ resid_out,
        const float* __restrict__ nw, const float* __restrict__ gsp,
        bf16* __restrict__ qout, float* __restrict__ yout, const int mode) {
    const int row  = blockIdx.x;
    const int tid  = threadIdx.x;
    const int lane = tid & 63;
    const int wave = tid >> 6;
    const float* x = in + (size_t)row * HD;

    float4 v[4];
    float ss = 0.0f;
#pragma unroll
    for (int c = 0; c < 4; c++) {
        v[c] = ((const float4*)x)[c * 256 + tid];
        if (mode == 0) {
            v[c].x = fmaxf(v[c].x, 0.0f);
            v[c].y = fmaxf(v[c].y, 0.0f);
            v[c].z = fmaxf(v[c].z, 0.0f);
            v[c].w = fmaxf(v[c].w, 0.0f);
        }
        ss += v[c].x * v[c].x + v[c].y * v[c].y + v[c].z * v[c].z + v[c].w * v[c].w;
    }
    if (mode == 0) {
        float4* r = (float4*)(resid_out + (size_t)row * HD);
#pragma unroll
        for (int c = 0; c < 4; c++) r[c * 256 + tid] = v[c];
    }
#pragma unroll
    for (int m = 1; m < 64; m <<= 1) ss += __shfl_xor(ss, m);
    __shared__ float sred[4];
    if (lane == 0) sred[wave] = ss;
    __syncthreads();
    const float total = sred[0] + sred[1] + sred[2] + sred[3];
    const float rs = rsqrtf(total * (1.0f / HD) + 1e-6f);
    const float gs = (mode == 2) ? 0.0f : *gsp;

#pragma unroll
    for (int c = 0; c < 4; c++) {
        const float4 nv = ((const float4*)nw)[c * 256 + tid];
        float4 y;
        y.x = v[c].x * rs * nv.x;
        y.y = v[c].y * rs * nv.y;
        y.z = v[c].z * rs * nv.z;
        y.w = v[c].w * rs * nv.w;
        if (mode == 2) {
            ((float4*)(yout + (size_t)row * HD))[c * 256 + tid] = y;
        } else {
            float am = fmaxf(fmaxf(fabsf(y.x), fabsf(y.y)), fmaxf(fabsf(y.z), fabsf(y.w)));
            am = fmaxf(am, __shfl_xor(am, 1));
            am = fmaxf(am, __shfl_xor(am, 2));
            const float sc = e4m3_round(fminf((am / 6.0f) * gs, 448.0f));
            bf16x4 o;
            if (sc > 0.0f) {
                o[0] = (bf16)(fp4_round(y.x * gs / sc) * sc);
                o[1] = (bf16)(fp4_round(y.y * gs / sc) * sc);
                o[2] = (bf16)(fp4_round(y.z * gs / sc) * sc);
                o[3] = (bf16)(fp4_round(y.w * gs / sc) * sc);
            } else {
                o[0] = o[1] = o[2] = o[3] = (bf16)0.0f;
            }
            ((bf16x4*)(qout + (size_t)row * HD))[c * 256 + tid] = o;
        }
    }
}

// ---------------------------------------------------------------------------
// C[M,N] = (A[M,K] @ B[N,K]^T) * alpha + C   (in-place residual add)
// m97 structure: 128x128 tile, BK=32, 4 waves in 2x2, 16x16x32 bf16 MFMA,
// global_load_lds width-16 staging (LDS layout = lane order, row-major 128x32).
__global__ __launch_bounds__(256) void gemm_bt_kernel(
        const bf16* __restrict__ A, const bf16* __restrict__ B,
        float* __restrict__ C,
        const float* __restrict__ agp, const float* __restrict__ wgp) {
    __shared__ __align__(16) bf16 sA[128 * 32];
    __shared__ __align__(16) bf16 sB[128 * 32];

    const int tid  = threadIdx.x;
    const int lane = tid & 63;
    const int wave = tid >> 6;
    const int tileM = blockIdx.x * 128;
    const int tileN = blockIdx.y * 128;
    const int waveM = (wave & 1) * 64;
    const int waveN = (wave >> 1) * 64;
    const int quad = lane >> 4;
    const int l16  = lane & 15;

    const float alpha = 1.0f / ((*wgp) * (*agp));

    f32x4 acc[4][4];
#pragma unroll
    for (int mi = 0; mi < 4; mi++)
#pragma unroll
        for (int ni = 0; ni < 4; ni++)
            acc[mi][ni] = (f32x4){0.0f, 0.0f, 0.0f, 0.0f};

    // staging: chunk ch = p*256 + tid covers row=ch>>2, cols (ch&3)*8..+8
    const int ch0 = tid,       row0 = ch0 >> 2, col0 = (ch0 & 3) * 8;
    const int ch1 = tid + 256, row1 = ch1 >> 2, col1 = (ch1 & 3) * 8;
    const bf16* gA0 = A + (size_t)(tileM + row0) * HD + col0;
    const bf16* gA1 = A + (size_t)(tileM + row1) * HD + col1;
    const bf16* gB0 = B + (size_t)(tileN + row0) * HD + col0;
    const bf16* gB1 = B + (size_t)(tileN + row1) * HD + col1;
    bf16* lA0 = &sA[(0 * 256 + wave * 64) * 8];   // wave-uniform LDS bases
    bf16* lA1 = &sA[(1 * 256 + wave * 64) * 8];
    bf16* lB0 = &sB[(0 * 256 + wave * 64) * 8];
    bf16* lB1 = &sB[(1 * 256 + wave * 64) * 8];

    for (int k0 = 0; k0 < HD; k0 += 32) {
        load_lds16(gA0 + k0, lA0);
        load_lds16(gA1 + k0, lA1);
        load_lds16(gB0 + k0, lB0);
        load_lds16(gB1 + k0, lB1);
        __syncthreads();

        bf16x8 aF[4], bF[4];
#pragma unroll
        for (int mi = 0; mi < 4; mi++)
            aF[mi] = *(const bf16x8*)&sA[(waveM + mi * 16 + l16) * 32 + quad * 8];
#pragma unroll
        for (int ni = 0; ni < 4; ni++)
            bF[ni] = *(const bf16x8*)&sB[(waveN + ni * 16 + l16) * 32 + quad * 8];
#pragma unroll
        for (int mi = 0; mi < 4; mi++)
#pragma unroll
            for (int ni = 0; ni < 4; ni++)
                acc[mi][ni] = __builtin_amdgcn_mfma_f32_16x16x32_bf16(
                    aF[mi], bF[ni], acc[mi][ni], 0, 0, 0);
        __syncthreads();
    }

    // epilogue: C/D layout col = lane&15, row = quad*4 + reg (m89/m91-verified)
#pragma unroll
    for (int mi = 0; mi < 4; mi++) {
#pragma unroll
        for (int ni = 0; ni < 4; ni++) {
            const int col  = tileN + waveN + ni * 16 + l16;
            const int rowb = tileM + waveM + mi * 16 + quad * 4;
#pragma unroll
            for (int r = 0; r < 4; r++) {
                const size_t idx = (size_t)(rowb + r) * HD + col;
                C[idx] = acc[mi][ni][r] * alpha + C[idx];
            }
        }
    }
}

// ---------------------------------------------------------------------------
extern "C" void kernel_launch(void* const* d_in, const int* in_sizes, int n_in,
                              void* d_out, int out_size, void* d_ws, size_t ws_size,
                              hipStream_t stream) {
    const float* hidden = (const float*)d_in[0];   // [T, H] fp32
    const float* norm_w = (const float*)d_in[1];   // [4, H]
    const float* w      = (const float*)d_in[2];   // [3, H, H]
    const float* ag     = (const float*)d_in[3];   // [3]
    const float* wg     = (const float*)d_in[4];   // [3]
    float* out = (float*)d_out;                    // reused as resid/x, then final y

    char* ws = (char*)d_ws;
    bf16* Bdeq = (bf16*)ws;                              // 3*H*H*2 = 100663296 B
    bf16* Adeq = (bf16*)(ws + (size_t)3 * HD * HD * 2);  // T*H*2   =  67108864 B

    // 1) weight quant+dequant (3*H*H/4 float4s / 256 threads)
    quant_w_kernel<<<(3 * HD * (HD / 4)) / 256, 256, 0, stream>>>(w, wg, Bdeq);

    // 2) relu + resid + rmsnorm(norm_w[0]) + quant(ag[0])
    rms_quant_kernel<<<TD, 256, 0, stream>>>(hidden, out, norm_w, ag, Adeq, nullptr, 0);

    // 3) three fused-FP4 GEMM layers
    const dim3 ggrid(TD / 128, HD / 128);
    for (int i = 0; i < 3; i++) {
        gemm_bt_kernel<<<ggrid, 256, 0, stream>>>(
            Adeq, Bdeq + (size_t)i * HD * HD, out, ag + i, wg + i);
        if (i < 2) {
            rms_quant_kernel<<<TD, 256, 0, stream>>>(
                out, nullptr, norm_w + (size_t)(i + 1) * HD, ag + (i + 1),
                Adeq, nullptr, 1);
        } else {
            rms_quant_kernel<<<TD, 256, 0, stream>>>(
                out, nullptr, norm_w + (size_t)3 * HD, nullptr,
                nullptr, out, 2);
        }
    }
    (void)in_sizes; (void)n_in; (void)out_size; (void)ws_size;
}